// Round 5
// baseline (505.256 us; speedup 1.0000x reference)
//
#include <hip/hip_runtime.h>
#include <hip/hip_bf16.h>
#include <hip/hip_fp16.h>
#include <math.h>

#define D_IN   128
#define D_RNI  32
#define HID    256
#define NCHUNK 8   // HID/32 channel chunks; rides blockIdx%8 -> XCD round-robin

typedef _Float16 half8 __attribute__((ext_vector_type(8)));
typedef float    f32x4 __attribute__((ext_vector_type(4)));

// ---------------------------------------------------------------------------
// Edge dtype detection: int64 edges (values < 2^31) have all odd words zero.
// ---------------------------------------------------------------------------
__global__ void k_detect(const unsigned int* __restrict__ w, int nwords, int* __restrict__ mode) {
    __shared__ unsigned int red[256];
    unsigned int acc = 0;
    for (int i = threadIdx.x; i < 1024; i += 256) {
        int idx = 2 * i + 1;
        if (idx < nwords) acc |= w[idx];
    }
    red[threadIdx.x] = acc;
    __syncthreads();
    for (int s = 128; s > 0; s >>= 1) {
        if (threadIdx.x < s) red[threadIdx.x] |= red[threadIdx.x + s];
        __syncthreads();
    }
    if (threadIdx.x == 0) *mode = (red[0] == 0u) ? 1 : 0;
}

__global__ void k_count(const unsigned int* __restrict__ ew, const int* __restrict__ mode_p,
                        int* __restrict__ counts, int e) {
    int mode = *mode_p;
    int i = blockIdx.x * 256 + threadIdx.x;
    if (i >= e) return;
    int d = mode ? (int)ew[2 * ((size_t)e + i)] : (int)ew[(size_t)e + i];
    atomicAdd(&counts[d], 1);
}

// ---------------------------------------------------------------------------
// Hierarchical scan
// ---------------------------------------------------------------------------
__global__ __launch_bounds__(1024) void k_scan1(const int* __restrict__ counts,
                                                int* __restrict__ incl,
                                                int* __restrict__ bsum, int n) {
    __shared__ int sd[1024];
    int t = threadIdx.x;
    int i = blockIdx.x * 1024 + t;
    int v = (i < n) ? counts[i] : 0;
    sd[t] = v;
    __syncthreads();
    for (int off = 1; off < 1024; off <<= 1) {
        int tmp = (t >= off) ? sd[t - off] : 0;
        __syncthreads();
        sd[t] += tmp;
        __syncthreads();
    }
    if (i < n) incl[i] = sd[t];
    if (t == 1023) bsum[blockIdx.x] = sd[1023];
}

__global__ __launch_bounds__(1024) void k_scan2(int* __restrict__ bsum, int nb) {
    __shared__ int sd[1024];
    int t = threadIdx.x;
    int v = (t < nb) ? bsum[t] : 0;
    sd[t] = v;
    __syncthreads();
    for (int off = 1; off < 1024; off <<= 1) {
        int tmp = (t >= off) ? sd[t - off] : 0;
        __syncthreads();
        sd[t] += tmp;
        __syncthreads();
    }
    if (t < nb) bsum[t] = sd[t] - v;
    if (t == nb - 1) bsum[nb] = sd[t];
}

__global__ void k_scan3(const int* __restrict__ counts, const int* __restrict__ incl,
                        const int* __restrict__ bsum,
                        int* __restrict__ rowptr, int* __restrict__ cursor,
                        float* __restrict__ dis, int n, int nb) {
    int i = blockIdx.x * 256 + threadIdx.x;
    if (i >= n) return;
    int excl = incl[i] - counts[i] + bsum[i >> 10];
    rowptr[i] = excl;
    cursor[i] = excl;
    dis[i] = 1.0f / sqrtf((float)(counts[i] + 1));
    if (i == 0) rowptr[n] = bsum[nb];
}

// Scatter edges into CSR grouped by dst; store (src, dis[src]*dis[dst]) packed.
__global__ void k_scatter(const unsigned int* __restrict__ ew, const int* __restrict__ mode_p,
                          int* __restrict__ cursor, const float* __restrict__ dis,
                          uint2* __restrict__ csrw, int e) {
    int mode = *mode_p;
    int i = blockIdx.x * 256 + threadIdx.x;
    if (i >= e) return;
    int s, d;
    if (mode) {
        s = (int)ew[2 * (size_t)i];
        d = (int)ew[2 * ((size_t)e + i)];
    } else {
        s = (int)ew[(size_t)i];
        d = (int)ew[(size_t)e + i];
    }
    float w = dis[s] * dis[d];
    int pos = atomicAdd(&cursor[d], 1);
    uint2 m;
    m.x = (unsigned int)s;
    m.y = __float_as_uint(w);
    csrw[pos] = m;
}

// W[K][N] fp32 -> Wt[N][K] fp16 (transpose + cast; tiny matrices)
__global__ void k_cvt_wt(const float* __restrict__ W, __half* __restrict__ Wt,
                         int K, int N, int total) {
    int i = blockIdx.x * 256 + threadIdx.x;
    if (i >= total) return;
    int k = i / N, nn = i - k * N;
    Wt[(size_t)nn * K + k] = __float2half(W[i]);
}

// ---------------------------------------------------------------------------
// fp16 MFMA GEMM: C[M x 256] = A[M x K] @ Bt^T  (Bt:[N=256][K] fp16).
// A_F32: A (+A2 concat at KA) fp32, cast during LDS staging.
// HALF_OUT: write fp16 in CHANNEL-CHUNKED layout [8][M][32] (for k_agg
// L2-locality); else fp32 row-major (+bias).
// Block: 256 thr = 4 waves; tile 64M x 256N; wave w owns N [64w,64w+64).
// ---------------------------------------------------------------------------
#define KT 32
#define LSTR 40
template <bool A_F32, bool ADD_BIAS, bool HALF_OUT>
__global__ __launch_bounds__(256) void k_mgemm(const void* __restrict__ Av, int strideA, int KA,
                                               const void* __restrict__ A2v, int strideA2,
                                               const __half* __restrict__ Bt,
                                               const float* __restrict__ bias,
                                               void* Cv, int M, int K) {
    __shared__ __half As[64 * LSTR];
    __shared__ __half Bs[256 * LSTR];
    int tid = threadIdx.x;
    int wave = tid >> 6, lane = tid & 63;
    int q = lane >> 4, m16 = lane & 15;
    int r0 = blockIdx.x * 64;

    f32x4 acc[4][4] = {};

    for (int k0 = 0; k0 < K; k0 += KT) {
        __syncthreads();
        {
            int r = tid >> 2, kq = (tid & 3) * 8;
            int row = r0 + r; if (row >= M) row = M - 1;
            if (A_F32) {
                const float* src; int stride, kk0;
                if (k0 < KA) { src = (const float*)Av;  stride = strideA;  kk0 = k0; }
                else         { src = (const float*)A2v; stride = strideA2; kk0 = k0 - KA; }
                const float* p = &src[(size_t)row * stride + kk0 + kq];
                float4 va = *reinterpret_cast<const float4*>(p);
                float4 vb = *reinterpret_cast<const float4*>(p + 4);
                union { __half2 h2[4]; uint4 u; } uu;
                uu.h2[0] = __floats2half2_rn(va.x, va.y);
                uu.h2[1] = __floats2half2_rn(va.z, va.w);
                uu.h2[2] = __floats2half2_rn(vb.x, vb.y);
                uu.h2[3] = __floats2half2_rn(vb.z, vb.w);
                *reinterpret_cast<uint4*>(&As[r * LSTR + kq]) = uu.u;
            } else {
                const __half* src = (const __half*)Av;
                uint4 v = *reinterpret_cast<const uint4*>(&src[(size_t)row * strideA + k0 + kq]);
                *reinterpret_cast<uint4*>(&As[r * LSTR + kq]) = v;
            }
        }
        {
            int nb = tid >> 2, kq = (tid & 3) * 8;
            #pragma unroll
            for (int i = 0; i < 4; ++i) {
                int nn = nb + i * 64;
                uint4 v = *reinterpret_cast<const uint4*>(&Bt[(size_t)nn * K + k0 + kq]);
                *reinterpret_cast<uint4*>(&Bs[nn * LSTR + kq]) = v;
            }
        }
        __syncthreads();

        half8 af[4], bf[4];
        #pragma unroll
        for (int mi = 0; mi < 4; ++mi)
            af[mi] = *reinterpret_cast<const half8*>(&As[(mi * 16 + m16) * LSTR + q * 8]);
        #pragma unroll
        for (int ni = 0; ni < 4; ++ni)
            bf[ni] = *reinterpret_cast<const half8*>(&Bs[(wave * 64 + ni * 16 + m16) * LSTR + q * 8]);
        #pragma unroll
        for (int mi = 0; mi < 4; ++mi)
            #pragma unroll
            for (int ni = 0; ni < 4; ++ni)
                acc[mi][ni] = __builtin_amdgcn_mfma_f32_16x16x32_f16(af[mi], bf[ni], acc[mi][ni], 0, 0, 0);
    }

    #pragma unroll
    for (int mi = 0; mi < 4; ++mi) {
        #pragma unroll
        for (int r = 0; r < 4; ++r) {
            int row = r0 + mi * 16 + q * 4 + r;
            if (row >= M) continue;
            #pragma unroll
            for (int ni = 0; ni < 4; ++ni) {
                int col = wave * 64 + ni * 16 + m16;
                float v = acc[mi][ni][r];
                if (ADD_BIAS) v += bias[col];
                if (HALF_OUT) {
                    // chunked layout: [chunk][row][32]
                    size_t addr = ((size_t)(col >> 5) * M + row) * 32 + (col & 31);
                    ((__half*)Cv)[addr] = __float2half(v);
                } else {
                    ((float*)Cv)[(size_t)row * HID + col] = v;
                }
            }
        }
    }
}

// ---------------------------------------------------------------------------
// Chunked aggregation. Input xh in [8][n][32] fp16; block's chunk = blockIdx&7
// (rides round-robin block->XCD dispatch: XCD k's L2 caches chunk k's 3.2 MB
// slice). Wave = 1 node x 4 sequential nodes; 8 edge sub-groups x 8 lanes
// (8B row-segment each); per-edge (src, w) precomputed in csrw. 8-way
// shfl_xor reduce; sub-group 0 writes row-major fp16 h.
// ---------------------------------------------------------------------------
__global__ __launch_bounds__(256) void k_agg(const __half* __restrict__ xh,
                                             const int* __restrict__ rowptr,
                                             const uint2* __restrict__ csrw,
                                             const float* __restrict__ dis,
                                             const float* __restrict__ bias,
                                             __half* __restrict__ outh, int n) {
    int chunk = blockIdx.x & 7;
    int g     = blockIdx.x >> 3;
    int wave = threadIdx.x >> 6, lane = threadIdx.x & 63;
    int sub = lane >> 3, cpos = lane & 7;
    const __half* base = xh + (size_t)chunk * n * 32;
    int cbase = chunk * 32 + cpos * 4;
    float4 bb = *reinterpret_cast<const float4*>(&bias[cbase]);

    #pragma unroll
    for (int t = 0; t < 4; ++t) {
        int i = g * 16 + wave * 4 + t;
        if (i >= n) break;                    // wave-uniform
        float disd = dis[i];
        int e0 = rowptr[i], e1 = rowptr[i + 1];

        // self term (sub 0 only; others contribute 0)
        uint2 sv = *reinterpret_cast<const uint2*>(&base[(size_t)i * 32 + cpos * 4]);
        float2 sf0 = __half22float2(*reinterpret_cast<__half2*>(&sv.x));
        float2 sf1 = __half22float2(*reinterpret_cast<__half2*>(&sv.y));
        float wself = (sub == 0) ? disd * disd : 0.0f;
        float a0 = sf0.x * wself, a1 = sf0.y * wself;
        float a2 = sf1.x * wself, a3 = sf1.y * wself;

        for (int e = e0; e < e1; e += 8) {
            int ee = e + sub;
            int idx = i; float w = 0.0f;
            if (ee < e1) {
                uint2 m = csrw[ee];
                idx = (int)m.x;
                w = __uint_as_float(m.y);
            }
            uint2 v = *reinterpret_cast<const uint2*>(&base[(size_t)idx * 32 + cpos * 4]);
            float2 f0 = __half22float2(*reinterpret_cast<__half2*>(&v.x));
            float2 f1 = __half22float2(*reinterpret_cast<__half2*>(&v.y));
            a0 = fmaf(f0.x, w, a0); a1 = fmaf(f0.y, w, a1);
            a2 = fmaf(f1.x, w, a2); a3 = fmaf(f1.y, w, a3);
        }

        // reduce across the 8 sub-groups (lane bits 3..5)
        a0 += __shfl_xor(a0, 8);  a1 += __shfl_xor(a1, 8);
        a2 += __shfl_xor(a2, 8);  a3 += __shfl_xor(a3, 8);
        a0 += __shfl_xor(a0, 16); a1 += __shfl_xor(a1, 16);
        a2 += __shfl_xor(a2, 16); a3 += __shfl_xor(a3, 16);
        a0 += __shfl_xor(a0, 32); a1 += __shfl_xor(a1, 32);
        a2 += __shfl_xor(a2, 32); a3 += __shfl_xor(a3, 32);

        if (sub == 0) {
            union { __half2 h2[2]; uint2 u; } o;
            o.h2[0] = __floats2half2_rn(fmaxf(a0 + bb.x, 0.0f), fmaxf(a1 + bb.y, 0.0f));
            o.h2[1] = __floats2half2_rn(fmaxf(a2 + bb.z, 0.0f), fmaxf(a3 + bb.w, 0.0f));
            *reinterpret_cast<uint2*>(&outh[(size_t)i * HID + cbase]) = o.u;
        }
    }
}

// ---------------------------------------------------------------------------
extern "C" void kernel_launch(void* const* d_in, const int* in_sizes, int n_in,
                              void* d_out, int out_size, void* d_ws, size_t ws_size,
                              hipStream_t stream) {
    const float* x     = (const float*)d_in[0];
    const float* rni   = (const float*)d_in[1];
    const unsigned int* ew = (const unsigned int*)d_in[2];
    const float* W1    = (const float*)d_in[3];
    const float* b1    = (const float*)d_in[4];
    const float* W2    = (const float*)d_in[5];
    const float* b2    = (const float*)d_in[6];
    const float* W_out = (const float*)d_in[7];
    const float* b_out = (const float*)d_in[8];
    float* out = (float*)d_out;

    const int n  = in_sizes[0] / D_IN;     // 50000
    const int e  = in_sizes[2] / 2;        // 800000
    const int nb = (n + 1023) / 1024;
    const int K1 = D_IN + D_RNI;           // 160

    char* ws = (char*)d_ws;
    size_t off = 0;
    auto carve = [&](size_t bytes) {
        char* p = ws + off;
        off = (off + bytes + 255) & ~(size_t)255;
        return p;
    };
    __half* xh    = (__half*)carve((size_t)n * HID * sizeof(__half));   // chunked [8][n][32]
    __half* h     = (__half*)carve((size_t)n * HID * sizeof(__half));   // row-major
    __half* W1t   = (__half*)carve((size_t)K1 * HID * sizeof(__half));
    __half* W2t   = (__half*)carve((size_t)HID * HID * sizeof(__half));
    __half* Wot   = (__half*)carve((size_t)HID * HID * sizeof(__half));
    int*   counts = (int*)carve((size_t)n * sizeof(int));
    int*   incl   = (int*)carve((size_t)n * sizeof(int));
    int*   bsum   = (int*)carve((size_t)(nb + 1) * sizeof(int));
    int*   rowptr = (int*)carve((size_t)(n + 1) * sizeof(int));
    int*   cursor = (int*)carve((size_t)n * sizeof(int));
    float* dis    = (float*)carve((size_t)n * sizeof(float));
    uint2* csrw   = (uint2*)carve((size_t)e * sizeof(uint2));
    int*   mode   = (int*)carve(sizeof(int));
    (void)ws_size;

    const int eb = (e + 255) / 256;
    const int gemm_blocks = (n + 63) / 64;
    const int agg_blocks  = NCHUNK * ((n + 15) / 16);

    // --- CSR build (with fused per-edge weight)
    k_detect<<<1, 256, 0, stream>>>(ew, 2 * e, mode);
    hipMemsetAsync(counts, 0, (size_t)n * sizeof(int), stream);
    k_count<<<eb, 256, 0, stream>>>(ew, mode, counts, e);
    k_scan1<<<nb, 1024, 0, stream>>>(counts, incl, bsum, n);
    k_scan2<<<1, 1024, 0, stream>>>(bsum, nb);
    k_scan3<<<(n + 255) / 256, 256, 0, stream>>>(counts, incl, bsum, rowptr, cursor, dis, n, nb);
    k_scatter<<<eb, 256, 0, stream>>>(ew, mode, cursor, dis, csrw, e);

    // --- weight transposes (tiny)
    {
        int tw1 = K1 * HID;
        k_cvt_wt<<<(tw1 + 255) / 256, 256, 0, stream>>>(W1, W1t, K1, HID, tw1);
        int tw = HID * HID;
        k_cvt_wt<<<(tw + 255) / 256, 256, 0, stream>>>(W2, W2t, HID, HID, tw);
        k_cvt_wt<<<(tw + 255) / 256, 256, 0, stream>>>(W_out, Wot, HID, HID, tw);
    }

    // --- layer 1
    k_mgemm<true, false, true><<<gemm_blocks, 256, 0, stream>>>(x, D_IN, D_IN, rni, D_RNI,
                                                                W1t, nullptr, xh, n, K1);
    k_agg<<<agg_blocks, 256, 0, stream>>>(xh, rowptr, csrw, dis, b1, h, n);

    // --- layer 2
    k_mgemm<false, false, true><<<gemm_blocks, 256, 0, stream>>>(h, HID, HID, nullptr, 0,
                                                                 W2t, nullptr, xh, n, HID);
    k_agg<<<agg_blocks, 256, 0, stream>>>(xh, rowptr, csrw, dis, b2, h, n);

    // --- output layer (fp32 out + bias)
    k_mgemm<false, true, false><<<gemm_blocks, 256, 0, stream>>>(h, HID, HID, nullptr, 0,
                                                                 Wot, b_out, out, n, HID);
}

// Round 6
// 394.074 us; speedup vs baseline: 1.2821x; 1.2821x over previous
//
#include <hip/hip_runtime.h>
#include <hip/hip_bf16.h>
#include <hip/hip_fp16.h>
#include <math.h>

#define D_IN   128
#define D_RNI  32
#define HID    256
#define NCHUNK 8   // HID/32 channel chunks; rides blockIdx%8 -> XCD round-robin

typedef _Float16 half8 __attribute__((ext_vector_type(8)));
typedef float    f32x4 __attribute__((ext_vector_type(4)));

// ---------------------------------------------------------------------------
// Fused: zero the counts array (whole grid) + edge dtype detection (block 0).
// int64 edges (values < 2^31) have all odd 32-bit words zero.
// ---------------------------------------------------------------------------
__global__ void k_detect_zero(const unsigned int* __restrict__ w, int nwords,
                              int* __restrict__ mode, int* __restrict__ counts, int n) {
    int i = blockIdx.x * 256 + threadIdx.x;
    if (i < n) counts[i] = 0;
    if (blockIdx.x == 0) {
        __shared__ unsigned int red[256];
        unsigned int acc = 0;
        for (int j = threadIdx.x; j < 1024; j += 256) {
            int idx = 2 * j + 1;
            if (idx < nwords) acc |= w[idx];
        }
        red[threadIdx.x] = acc;
        __syncthreads();
        for (int s = 128; s > 0; s >>= 1) {
            if (threadIdx.x < s) red[threadIdx.x] |= red[threadIdx.x + s];
            __syncthreads();
        }
        if (threadIdx.x == 0) *mode = (red[0] == 0u) ? 1 : 0;
    }
}

__global__ void k_count(const unsigned int* __restrict__ ew, const int* __restrict__ mode_p,
                        int* __restrict__ counts, int e) {
    int mode = *mode_p;
    int i = blockIdx.x * 256 + threadIdx.x;
    if (i >= e) return;
    int d = mode ? (int)ew[2 * ((size_t)e + i)] : (int)ew[(size_t)e + i];
    atomicAdd(&counts[d], 1);
}

// ---------------------------------------------------------------------------
// Hierarchical scan
// ---------------------------------------------------------------------------
__global__ __launch_bounds__(1024) void k_scan1(const int* __restrict__ counts,
                                                int* __restrict__ incl,
                                                int* __restrict__ bsum, int n) {
    __shared__ int sd[1024];
    int t = threadIdx.x;
    int i = blockIdx.x * 1024 + t;
    int v = (i < n) ? counts[i] : 0;
    sd[t] = v;
    __syncthreads();
    for (int off = 1; off < 1024; off <<= 1) {
        int tmp = (t >= off) ? sd[t - off] : 0;
        __syncthreads();
        sd[t] += tmp;
        __syncthreads();
    }
    if (i < n) incl[i] = sd[t];
    if (t == 1023) bsum[blockIdx.x] = sd[1023];
}

__global__ __launch_bounds__(1024) void k_scan2(int* __restrict__ bsum, int nb) {
    __shared__ int sd[1024];
    int t = threadIdx.x;
    int v = (t < nb) ? bsum[t] : 0;
    sd[t] = v;
    __syncthreads();
    for (int off = 1; off < 1024; off <<= 1) {
        int tmp = (t >= off) ? sd[t - off] : 0;
        __syncthreads();
        sd[t] += tmp;
        __syncthreads();
    }
    if (t < nb) bsum[t] = sd[t] - v;
    if (t == nb - 1) bsum[nb] = sd[t];
}

__global__ void k_scan3(const int* __restrict__ counts, const int* __restrict__ incl,
                        const int* __restrict__ bsum,
                        int* __restrict__ rowptr, int* __restrict__ cursor,
                        float* __restrict__ dis, int n, int nb) {
    int i = blockIdx.x * 256 + threadIdx.x;
    if (i >= n) return;
    int excl = incl[i] - counts[i] + bsum[i >> 10];
    rowptr[i] = excl;
    cursor[i] = excl;
    dis[i] = 1.0f / sqrtf((float)(counts[i] + 1));
    if (i == 0) rowptr[n] = bsum[nb];
}

// Scatter edges into CSR grouped by dst; store (src, dis[src]*dis[dst]) packed.
__global__ void k_scatter(const unsigned int* __restrict__ ew, const int* __restrict__ mode_p,
                          int* __restrict__ cursor, const float* __restrict__ dis,
                          uint2* __restrict__ csrw, int e) {
    int mode = *mode_p;
    int i = blockIdx.x * 256 + threadIdx.x;
    if (i >= e) return;
    int s, d;
    if (mode) {
        s = (int)ew[2 * (size_t)i];
        d = (int)ew[2 * ((size_t)e + i)];
    } else {
        s = (int)ew[(size_t)i];
        d = (int)ew[(size_t)e + i];
    }
    float w = dis[s] * dis[d];
    int pos = atomicAdd(&cursor[d], 1);
    uint2 m;
    m.x = (unsigned int)s;
    m.y = __float_as_uint(w);
    csrw[pos] = m;
}

// All three weight transposes (fp32 W[K][N] -> fp16 Wt[N][K]) in ONE launch.
#define TW1 (160 * 256)
#define TW2 (256 * 256)
__global__ void k_cvt_all(const float* __restrict__ W1, const float* __restrict__ W2,
                          const float* __restrict__ Wo,
                          __half* __restrict__ W1t, __half* __restrict__ W2t,
                          __half* __restrict__ Wot) {
    int i = blockIdx.x * 256 + threadIdx.x;
    if (i < TW1) {
        int k = i / 256, nn = i & 255;
        W1t[(size_t)nn * 160 + k] = __float2half(W1[i]);
    } else if (i < TW1 + TW2) {
        int j = i - TW1;
        int k = j >> 8, nn = j & 255;
        W2t[(size_t)nn * 256 + k] = __float2half(W2[j]);
    } else if (i < TW1 + 2 * TW2) {
        int j = i - TW1 - TW2;
        int k = j >> 8, nn = j & 255;
        Wot[(size_t)nn * 256 + k] = __float2half(Wo[j]);
    }
}

// ---------------------------------------------------------------------------
// fp16 MFMA GEMM: C[M x 256] = A[M x K] @ Bt^T  (Bt:[N=256][K] fp16).
// A_F32: A (+A2 concat at KA) fp32, cast during LDS staging.
// HALF_OUT: write fp16 in CHANNEL-CHUNKED layout [8][M][32]; else fp32 (+bias).
// Block: 256 thr = 4 waves; tile 64M x 256N; wave w owns N [64w,64w+64).
// ---------------------------------------------------------------------------
#define KT 32
#define LSTR 40
template <bool A_F32, bool ADD_BIAS, bool HALF_OUT>
__global__ __launch_bounds__(256) void k_mgemm(const void* __restrict__ Av, int strideA, int KA,
                                               const void* __restrict__ A2v, int strideA2,
                                               const __half* __restrict__ Bt,
                                               const float* __restrict__ bias,
                                               void* Cv, int M, int K) {
    __shared__ __half As[64 * LSTR];
    __shared__ __half Bs[256 * LSTR];
    int tid = threadIdx.x;
    int wave = tid >> 6, lane = tid & 63;
    int q = lane >> 4, m16 = lane & 15;
    int r0 = blockIdx.x * 64;

    f32x4 acc[4][4] = {};

    for (int k0 = 0; k0 < K; k0 += KT) {
        __syncthreads();
        {
            int r = tid >> 2, kq = (tid & 3) * 8;
            int row = r0 + r; if (row >= M) row = M - 1;
            if (A_F32) {
                const float* src; int stride, kk0;
                if (k0 < KA) { src = (const float*)Av;  stride = strideA;  kk0 = k0; }
                else         { src = (const float*)A2v; stride = strideA2; kk0 = k0 - KA; }
                const float* p = &src[(size_t)row * stride + kk0 + kq];
                float4 va = *reinterpret_cast<const float4*>(p);
                float4 vb = *reinterpret_cast<const float4*>(p + 4);
                union { __half2 h2[4]; uint4 u; } uu;
                uu.h2[0] = __floats2half2_rn(va.x, va.y);
                uu.h2[1] = __floats2half2_rn(va.z, va.w);
                uu.h2[2] = __floats2half2_rn(vb.x, vb.y);
                uu.h2[3] = __floats2half2_rn(vb.z, vb.w);
                *reinterpret_cast<uint4*>(&As[r * LSTR + kq]) = uu.u;
            } else {
                const __half* src = (const __half*)Av;
                uint4 v = *reinterpret_cast<const uint4*>(&src[(size_t)row * strideA + k0 + kq]);
                *reinterpret_cast<uint4*>(&As[r * LSTR + kq]) = v;
            }
        }
        {
            int nb = tid >> 2, kq = (tid & 3) * 8;
            #pragma unroll
            for (int i = 0; i < 4; ++i) {
                int nn = nb + i * 64;
                uint4 v = *reinterpret_cast<const uint4*>(&Bt[(size_t)nn * K + k0 + kq]);
                *reinterpret_cast<uint4*>(&Bs[nn * LSTR + kq]) = v;
            }
        }
        __syncthreads();

        half8 af[4], bf[4];
        #pragma unroll
        for (int mi = 0; mi < 4; ++mi)
            af[mi] = *reinterpret_cast<const half8*>(&As[(mi * 16 + m16) * LSTR + q * 8]);
        #pragma unroll
        for (int ni = 0; ni < 4; ++ni)
            bf[ni] = *reinterpret_cast<const half8*>(&Bs[(wave * 64 + ni * 16 + m16) * LSTR + q * 8]);
        #pragma unroll
        for (int mi = 0; mi < 4; ++mi)
            #pragma unroll
            for (int ni = 0; ni < 4; ++ni)
                acc[mi][ni] = __builtin_amdgcn_mfma_f32_16x16x32_f16(af[mi], bf[ni], acc[mi][ni], 0, 0, 0);
    }

    #pragma unroll
    for (int mi = 0; mi < 4; ++mi) {
        #pragma unroll
        for (int r = 0; r < 4; ++r) {
            int row = r0 + mi * 16 + q * 4 + r;
            if (row >= M) continue;
            #pragma unroll
            for (int ni = 0; ni < 4; ++ni) {
                int col = wave * 64 + ni * 16 + m16;
                float v = acc[mi][ni][r];
                if (ADD_BIAS) v += bias[col];
                if (HALF_OUT) {
                    size_t addr = ((size_t)(col >> 5) * M + row) * 32 + (col & 31);
                    ((__half*)Cv)[addr] = __float2half(v);
                } else {
                    ((float*)Cv)[(size_t)row * HID + col] = v;
                }
            }
        }
    }
}

// ---------------------------------------------------------------------------
// Chunked aggregation, SUB-GROUP-PER-NODE (no shfl, no LDS, no barriers).
// xh chunked [8][n][32] fp16; chunk = blockIdx&7 (XCD round-robin -> each
// XCD's L2 caches one 3.2 MB slice). Block = 32 sub-groups of 8 lanes; each
// sub-group owns one node's 32-channel slice (lane = 4 ch, 8 B loads). Lane
// accumulates privately across edges -> result complete without reduction.
// Edge loop unrolled x4: 4 csrw loads then 4 gathers in flight.
// ---------------------------------------------------------------------------
__global__ __launch_bounds__(256) void k_agg(const __half* __restrict__ xh,
                                             const int* __restrict__ rowptr,
                                             const uint2* __restrict__ csrw,
                                             const float* __restrict__ dis,
                                             const float* __restrict__ bias,
                                             __half* __restrict__ outh, int n) {
    int chunk = blockIdx.x & 7;
    int g     = blockIdx.x >> 3;
    int sub   = threadIdx.x >> 3;        // 0..31
    int cpos  = threadIdx.x & 7;         // 0..7
    int i = g * 32 + sub;
    if (i >= n) return;

    const __half* base = xh + (size_t)chunk * n * 32;
    float disd = dis[i];
    int e0 = rowptr[i], e1 = rowptr[i + 1];

    float a0, a1, a2, a3;
    {
        uint2 sv = *reinterpret_cast<const uint2*>(&base[(size_t)i * 32 + cpos * 4]);
        float2 f0 = __half22float2(*reinterpret_cast<__half2*>(&sv.x));
        float2 f1 = __half22float2(*reinterpret_cast<__half2*>(&sv.y));
        float ws = disd * disd;
        a0 = f0.x * ws; a1 = f0.y * ws; a2 = f1.x * ws; a3 = f1.y * ws;
    }

    int ee = e0;
    for (; ee + 4 <= e1; ee += 4) {
        uint2 m0 = csrw[ee + 0];
        uint2 m1 = csrw[ee + 1];
        uint2 m2 = csrw[ee + 2];
        uint2 m3 = csrw[ee + 3];
        uint2 v0 = *reinterpret_cast<const uint2*>(&base[(size_t)m0.x * 32 + cpos * 4]);
        uint2 v1 = *reinterpret_cast<const uint2*>(&base[(size_t)m1.x * 32 + cpos * 4]);
        uint2 v2 = *reinterpret_cast<const uint2*>(&base[(size_t)m2.x * 32 + cpos * 4]);
        uint2 v3 = *reinterpret_cast<const uint2*>(&base[(size_t)m3.x * 32 + cpos * 4]);
        float w0 = __uint_as_float(m0.y), w1 = __uint_as_float(m1.y);
        float w2 = __uint_as_float(m2.y), w3 = __uint_as_float(m3.y);
        float2 p0 = __half22float2(*reinterpret_cast<__half2*>(&v0.x));
        float2 q0 = __half22float2(*reinterpret_cast<__half2*>(&v0.y));
        float2 p1 = __half22float2(*reinterpret_cast<__half2*>(&v1.x));
        float2 q1 = __half22float2(*reinterpret_cast<__half2*>(&v1.y));
        float2 p2 = __half22float2(*reinterpret_cast<__half2*>(&v2.x));
        float2 q2 = __half22float2(*reinterpret_cast<__half2*>(&v2.y));
        float2 p3 = __half22float2(*reinterpret_cast<__half2*>(&v3.x));
        float2 q3 = __half22float2(*reinterpret_cast<__half2*>(&v3.y));
        a0 = fmaf(p0.x, w0, a0); a1 = fmaf(p0.y, w0, a1);
        a2 = fmaf(q0.x, w0, a2); a3 = fmaf(q0.y, w0, a3);
        a0 = fmaf(p1.x, w1, a0); a1 = fmaf(p1.y, w1, a1);
        a2 = fmaf(q1.x, w1, a2); a3 = fmaf(q1.y, w1, a3);
        a0 = fmaf(p2.x, w2, a0); a1 = fmaf(p2.y, w2, a1);
        a2 = fmaf(q2.x, w2, a2); a3 = fmaf(q2.y, w2, a3);
        a0 = fmaf(p3.x, w3, a0); a1 = fmaf(p3.y, w3, a1);
        a2 = fmaf(q3.x, w3, a2); a3 = fmaf(q3.y, w3, a3);
    }
    for (; ee < e1; ++ee) {
        uint2 m = csrw[ee];
        float w = __uint_as_float(m.y);
        uint2 v = *reinterpret_cast<const uint2*>(&base[(size_t)m.x * 32 + cpos * 4]);
        float2 p = __half22float2(*reinterpret_cast<__half2*>(&v.x));
        float2 q = __half22float2(*reinterpret_cast<__half2*>(&v.y));
        a0 = fmaf(p.x, w, a0); a1 = fmaf(p.y, w, a1);
        a2 = fmaf(q.x, w, a2); a3 = fmaf(q.y, w, a3);
    }

    int cbase = chunk * 32 + cpos * 4;
    float4 bb = *reinterpret_cast<const float4*>(&bias[cbase]);
    union { __half2 h2[2]; uint2 u; } o;
    o.h2[0] = __floats2half2_rn(fmaxf(a0 + bb.x, 0.0f), fmaxf(a1 + bb.y, 0.0f));
    o.h2[1] = __floats2half2_rn(fmaxf(a2 + bb.z, 0.0f), fmaxf(a3 + bb.w, 0.0f));
    *reinterpret_cast<uint2*>(&outh[(size_t)i * HID + cbase]) = o.u;
}

// ---------------------------------------------------------------------------
extern "C" void kernel_launch(void* const* d_in, const int* in_sizes, int n_in,
                              void* d_out, int out_size, void* d_ws, size_t ws_size,
                              hipStream_t stream) {
    const float* x     = (const float*)d_in[0];
    const float* rni   = (const float*)d_in[1];
    const unsigned int* ew = (const unsigned int*)d_in[2];
    const float* W1    = (const float*)d_in[3];
    const float* b1    = (const float*)d_in[4];
    const float* W2    = (const float*)d_in[5];
    const float* b2    = (const float*)d_in[6];
    const float* W_out = (const float*)d_in[7];
    const float* b_out = (const float*)d_in[8];
    float* out = (float*)d_out;

    const int n  = in_sizes[0] / D_IN;     // 50000
    const int e  = in_sizes[2] / 2;        // 800000
    const int nb = (n + 1023) / 1024;
    const int K1 = D_IN + D_RNI;           // 160

    char* ws = (char*)d_ws;
    size_t off = 0;
    auto carve = [&](size_t bytes) {
        char* p = ws + off;
        off = (off + bytes + 255) & ~(size_t)255;
        return p;
    };
    __half* xh    = (__half*)carve((size_t)n * HID * sizeof(__half));   // chunked [8][n][32]
    __half* h     = (__half*)carve((size_t)n * HID * sizeof(__half));   // row-major
    __half* W1t   = (__half*)carve((size_t)K1 * HID * sizeof(__half));
    __half* W2t   = (__half*)carve((size_t)HID * HID * sizeof(__half));
    __half* Wot   = (__half*)carve((size_t)HID * HID * sizeof(__half));
    int*   counts = (int*)carve((size_t)n * sizeof(int));
    int*   incl   = (int*)carve((size_t)n * sizeof(int));
    int*   bsum   = (int*)carve((size_t)(nb + 1) * sizeof(int));
    int*   rowptr = (int*)carve((size_t)(n + 1) * sizeof(int));
    int*   cursor = (int*)carve((size_t)n * sizeof(int));
    float* dis    = (float*)carve((size_t)n * sizeof(float));
    uint2* csrw   = (uint2*)carve((size_t)e * sizeof(uint2));
    int*   mode   = (int*)carve(sizeof(int));
    (void)ws_size;

    const int eb = (e + 255) / 256;
    const int gemm_blocks = (n + 63) / 64;
    const int agg_blocks  = NCHUNK * ((n + 31) / 32);

    // --- CSR build (fused zero+detect; per-edge weight fused into scatter)
    k_detect_zero<<<(n + 255) / 256, 256, 0, stream>>>(ew, 2 * e, mode, counts, n);
    k_count<<<eb, 256, 0, stream>>>(ew, mode, counts, e);
    k_scan1<<<nb, 1024, 0, stream>>>(counts, incl, bsum, n);
    k_scan2<<<1, 1024, 0, stream>>>(bsum, nb);
    k_scan3<<<(n + 255) / 256, 256, 0, stream>>>(counts, incl, bsum, rowptr, cursor, dis, n, nb);
    k_scatter<<<eb, 256, 0, stream>>>(ew, mode, cursor, dis, csrw, e);

    // --- all weight transposes in one launch
    {
        int tot = TW1 + 2 * TW2;
        k_cvt_all<<<(tot + 255) / 256, 256, 0, stream>>>(W1, W2, W_out, W1t, W2t, Wot);
    }

    // --- layer 1
    k_mgemm<true, false, true><<<gemm_blocks, 256, 0, stream>>>(x, D_IN, D_IN, rni, D_RNI,
                                                                W1t, nullptr, xh, n, K1);
    k_agg<<<agg_blocks, 256, 0, stream>>>(xh, rowptr, csrw, dis, b1, h, n);

    // --- layer 2
    k_mgemm<false, false, true><<<gemm_blocks, 256, 0, stream>>>(h, HID, HID, nullptr, 0,
                                                                 W2t, nullptr, xh, n, HID);
    k_agg<<<agg_blocks, 256, 0, stream>>>(xh, rowptr, csrw, dis, b2, h, n);

    // --- output layer (fp32 out + bias)
    k_mgemm<false, true, false><<<gemm_blocks, 256, 0, stream>>>(h, HID, HID, nullptr, 0,
                                                                 Wot, b_out, out, n, HID);
}